// Round 1
// baseline (246.538 us; speedup 1.0000x reference)
//
#include <hip/hip_runtime.h>
#include <math.h>

#define HW    262144
#define MROWS 100
#define NCOLS 50
#define OUTSZ (MROWS * NCOLS)

typedef __attribute__((ext_vector_type(8))) short bf16x8;
typedef __attribute__((ext_vector_type(4))) float f32x4;

__device__ __forceinline__ unsigned short f32_bf16(float x) {
  unsigned int u = __float_as_uint(x);
  u += 0x7FFFu + ((u >> 16) & 1u);          // RNE to bf16
  return (unsigned short)(u >> 16);
}
__device__ __forceinline__ float bf16_f32(unsigned short h) {
  return __uint_as_float(((unsigned int)h) << 16);
}
__device__ __forceinline__ void split_frag(const float4& v0, const float4& v1,
                                           bf16x8& hi, bf16x8& lo) {
  float xs[8] = {v0.x, v0.y, v0.z, v0.w, v1.x, v1.y, v1.z, v1.w};
#pragma unroll
  for (int j = 0; j < 8; ++j) {
    unsigned short h = f32_bf16(xs[j]);
    hi[j] = (short)h;
    lo[j] = (short)f32_bf16(xs[j] - bf16_f32(h));
  }
}

// Phase 1: per-block K-chunk partial GEMM. Block = 4 waves, wave-grid 2x2,
// each wave owns 64 rows x 32 cols of the (112x64-padded) 100x50 output.
// Fragments gathered directly from global (fp32) -> split to bf16 hi/lo ->
// 3-pass MFMA accumulation in fp32.
__global__ __launch_bounds__(256, 2) void dm_phase1(
    const float* __restrict__ pred, const float* __restrict__ gt,
    float* __restrict__ partial, int chunk) {
  const int b    = blockIdx.x;
  const int tid  = threadIdx.x;
  const int lane = tid & 63;
  const int wid  = tid >> 6;
  const int wi = wid >> 1, wj = wid & 1;
  const int g = lane >> 4, r = lane & 15;

  long k0 = (long)b * chunk;
  long kend = k0 + chunk;
  if (kend > (long)HW) kend = HW;

  const float* pA[4];
  bool okA[4];
#pragma unroll
  for (int mf = 0; mf < 4; ++mf) {
    int row = wi * 64 + mf * 16 + r;
    okA[mf] = row < MROWS;
    pA[mf] = pred + (size_t)(okA[mf] ? row : 0) * HW + g * 8;
  }
  const float* pB[2];
  bool okB[2];
#pragma unroll
  for (int nf = 0; nf < 2; ++nf) {
    int col = wj * 32 + nf * 16 + r;
    okB[nf] = col < NCOLS;
    pB[nf] = gt + (size_t)(okB[nf] ? col : 0) * HW + g * 8;
  }

  f32x4 acc[4][2] = {};

  auto LD = [&](long kk, float4 (&A)[4][2], float4 (&B)[2][2]) {
#pragma unroll
    for (int mf = 0; mf < 4; ++mf) {
      if (wi == 0 || mf < 3) {              // skip all-invalid frag (rows 112..127)
        const float4* q = reinterpret_cast<const float4*>(pA[mf] + kk);
        float4 v0 = q[0], v1 = q[1];
        if (!okA[mf]) { v0 = make_float4(0.f,0.f,0.f,0.f); v1 = v0; }
        A[mf][0] = v0; A[mf][1] = v1;
      }
    }
#pragma unroll
    for (int nf = 0; nf < 2; ++nf) {
      const float4* q = reinterpret_cast<const float4*>(pB[nf] + kk);
      float4 v0 = q[0], v1 = q[1];
      if (!okB[nf]) { v0 = make_float4(0.f,0.f,0.f,0.f); v1 = v0; }
      B[nf][0] = v0; B[nf][1] = v1;
    }
  };

  auto STEP = [&](float4 (&A)[4][2], float4 (&B)[2][2]) {
    bf16x8 bh[2], bl[2];
#pragma unroll
    for (int nf = 0; nf < 2; ++nf) split_frag(B[nf][0], B[nf][1], bh[nf], bl[nf]);
#pragma unroll
    for (int mf = 0; mf < 4; ++mf) {
      if (wi == 0 || mf < 3) {
        bf16x8 ah, al;
        split_frag(A[mf][0], A[mf][1], ah, al);
#pragma unroll
        for (int nf = 0; nf < 2; ++nf) {
          acc[mf][nf] = __builtin_amdgcn_mfma_f32_16x16x32_bf16(ah, bh[nf], acc[mf][nf], 0, 0, 0);
          acc[mf][nf] = __builtin_amdgcn_mfma_f32_16x16x32_bf16(al, bh[nf], acc[mf][nf], 0, 0, 0);
          acc[mf][nf] = __builtin_amdgcn_mfma_f32_16x16x32_bf16(ah, bl[nf], acc[mf][nf], 0, 0, 0);
        }
      }
    }
  };

  // register double-buffered K loop (K-step = 32, unrolled by 2)
  float4 A0[4][2], B0[2][2], A1[4][2], B1[2][2];
  if (k0 < kend) LD(k0, A0, B0);
  for (long k = k0; k < kend; k += 64) {
    if (k + 32 < kend) LD(k + 32, A1, B1);
    STEP(A0, B0);
    if (k + 32 < kend) {
      if (k + 64 < kend) LD(k + 64, A0, B0);
      STEP(A1, B1);
    }
  }

  // epilogue: C/D layout col = lane&15, row = 4*(lane>>4)+reg  [m89-verified]
#pragma unroll
  for (int mf = 0; mf < 4; ++mf) {
#pragma unroll
    for (int nf = 0; nf < 2; ++nf) {
#pragma unroll
      for (int q = 0; q < 4; ++q) {
        int row = wi * 64 + mf * 16 + g * 4 + q;
        int col = wj * 32 + nf * 16 + r;
        if (row < MROWS && col < NCOLS)
          partial[(size_t)b * OUTSZ + row * NCOLS + col] = acc[mf][nf][q];
      }
    }
  }
}

// Phase 2a: reduce per-block partials in double, form log_alpha = (dot-1)/TEMP
__global__ void dm_reduce(const float* __restrict__ partial,
                          double* __restrict__ la, int nblk) {
  int p = blockIdx.x * blockDim.x + threadIdx.x;
  if (p >= OUTSZ) return;
  double s = 0.0;
  for (int b = 0; b < nblk; ++b) s += (double)partial[(size_t)b * OUTSZ + p];
  la[p] = (s - 1.0) * 10.0;   // -(1-dot)/0.1
}

// Phase 2b: 5 Sinkhorn iterations on [100][50] in double, then exp -> out
__global__ __launch_bounds__(1024) void dm_sinkhorn(const double* __restrict__ la_in,
                                                    float* __restrict__ out) {
  __shared__ double la[OUTSZ];
  __shared__ double lser[MROWS];
  __shared__ double lsec[NCOLS];
  const int t = threadIdx.x;
  for (int p = t; p < OUTSZ; p += 1024) la[p] = la_in[p];
  __syncthreads();
  for (int it = 0; it < 5; ++it) {
    // rows: lse over N (axis 2). 100 rows x 8 lanes.
    if (t < 800) {
      int row = t >> 3, sl = t & 7;
      double m = -1e300, s = 0.0;
      for (int n = sl; n < NCOLS; n += 8) {
        double v = la[row * NCOLS + n];
        if (v > m) { s = s * exp(m - v) + 1.0; m = v; }
        else s += exp(v - m);
      }
#pragma unroll
      for (int d = 1; d < 8; d <<= 1) {
        double mo = __shfl_xor(m, d, 64);
        double so = __shfl_xor(s, d, 64);
        double mn = fmax(m, mo);
        s = s * exp(m - mn) + so * exp(mo - mn);
        m = mn;
      }
      if (sl == 0) lser[row] = m + log(s);
    }
    __syncthreads();
    for (int p = t; p < OUTSZ; p += 1024) la[p] -= lser[p / NCOLS];
    __syncthreads();
    // cols: lse over K (axis 1). 50 cols x 16 lanes.
    if (t < 800) {
      int col = t >> 4, sl = t & 15;
      double m = -1e300, s = 0.0;
      for (int rr = sl; rr < MROWS; rr += 16) {
        double v = la[rr * NCOLS + col];
        if (v > m) { s = s * exp(m - v) + 1.0; m = v; }
        else s += exp(v - m);
      }
#pragma unroll
      for (int d = 1; d < 16; d <<= 1) {
        double mo = __shfl_xor(m, d, 64);
        double so = __shfl_xor(s, d, 64);
        double mn = fmax(m, mo);
        s = s * exp(m - mn) + so * exp(mo - mn);
        m = mn;
      }
      if (sl == 0) lsec[col] = m + log(s);
    }
    __syncthreads();
    for (int p = t; p < OUTSZ; p += 1024) la[p] -= lsec[p % NCOLS];
    __syncthreads();
  }
  for (int p = t; p < OUTSZ; p += 1024) out[p] = (float)exp(la[p]);
}

extern "C" void kernel_launch(void* const* d_in, const int* in_sizes, int n_in,
                              void* d_out, int out_size, void* d_ws, size_t ws_size,
                              hipStream_t stream) {
  const float* pred = (const float*)d_in[0];   // [1,100,512,512] fp32
  const float* gt   = (const float*)d_in[1];   // [50,512,512]    fp32
  float* out = (float*)d_out;                  // [1,100,50]      fp32

  int nblk = 512;
  while (nblk > 1 &&
         ((size_t)nblk * OUTSZ * sizeof(float) + OUTSZ * sizeof(double)) > ws_size)
    nblk >>= 1;
  int chunk = (HW + nblk - 1) / nblk;
  chunk = ((chunk + 63) / 64) * 64;            // even number of 32-wide K-steps

  float*  partial = (float*)d_ws;
  double* la = (double*)((char*)d_ws + (size_t)nblk * OUTSZ * sizeof(float));

  dm_phase1<<<nblk, 256, 0, stream>>>(pred, gt, partial, chunk);
  dm_reduce<<<(OUTSZ + 255) / 256, 256, 0, stream>>>(partial, la, nblk);
  dm_sinkhorn<<<1, 1024, 0, stream>>>(la, out);
}

// Round 2
// 85.724 us; speedup vs baseline: 2.8760x; 2.8760x over previous
//
#include <hip/hip_runtime.h>
#include <math.h>

#define HW    262144
#define MROWS 100
#define NCOLS 50
#define OUTSZ (MROWS * NCOLS)

typedef __attribute__((ext_vector_type(8))) short bf16x8;
typedef __attribute__((ext_vector_type(4))) float f32x4;

__device__ __forceinline__ unsigned short f32_bf16(float x) {
  unsigned int u = __float_as_uint(x);
  u += 0x7FFFu + ((u >> 16) & 1u);          // RNE to bf16
  return (unsigned short)(u >> 16);
}
__device__ __forceinline__ float bf16_f32(unsigned short h) {
  return __uint_as_float(((unsigned int)h) << 16);
}
__device__ __forceinline__ void split_frag(const float4& v0, const float4& v1,
                                           bf16x8& hi, bf16x8& lo) {
  float xs[8] = {v0.x, v0.y, v0.z, v0.w, v1.x, v1.y, v1.z, v1.w};
#pragma unroll
  for (int j = 0; j < 8; ++j) {
    unsigned short h = f32_bf16(xs[j]);
    hi[j] = (short)h;
    lo[j] = (short)f32_bf16(xs[j] - bf16_f32(h));
  }
}

// ---------------------------------------------------------------------------
// Phase 1: LDS-staged split-K GEMM.
// Block = 256 thr (4 waves, 2x2 wave grid) covering the full 112x64-padded
// 100x50 output; each block owns a K-chunk.
// BK=32 floats/row/stage. LDS per buffer: A 112 rows + B 64 rows, 128 B each,
// +dummy pad = 24576 B; double-buffered = 48 KB -> 3 blocks/CU.
// Staged via global_load_lds(16B): linear LDS dest, inverse-XOR-swizzled
// global source; ds_read_b128 with byte ^= ((row&7)<<4)  -> 2-way conflicts.
// Pipeline: counted s_waitcnt vmcnt(6) + raw s_barrier (2 barriers/stage) so
// next-stage loads stay in flight across the barrier (no vmcnt(0) drain).
// ---------------------------------------------------------------------------
#define ABYTES   14336          // 896 slots * 16 (rows 0..111)
#define BUFBYTES 24576          // 1536 slots * 16
#define SLOT_ITERS 6            // 1536 slots / 256 threads

typedef __attribute__((address_space(1))) const unsigned int GU32;
typedef __attribute__((address_space(3))) unsigned int LU32;

__global__ __launch_bounds__(256, 3) void dm_phase1(
    const float* __restrict__ pred, const float* __restrict__ gt,
    float* __restrict__ partial, int chunk) {
  __shared__ unsigned char smem[2 * BUFBYTES];

  const int b    = blockIdx.x;
  const int tid  = threadIdx.x;
  const int lane = tid & 63;
  const int wid  = tid >> 6;
  const int wi = wid >> 1, wj = wid & 1;
  const int g = lane >> 4, r = lane & 15;

  const int kbase = b * chunk;
  const int nst   = chunk >> 5;             // stages of BK=32

  // per-lane staging source base pointers (k-offset added per stage)
  const float* srcb[SLOT_ITERS];
#pragma unroll
  for (int it = 0; it < SLOT_ITERS; ++it) {
    int s = it * 256 + tid;
    if (s < 896) {                          // A region, rows 0..111
      int row = s >> 3, t = s & 7;
      int rr = row < MROWS ? row : MROWS - 1;
      srcb[it] = pred + (size_t)rr * HW + ((t ^ (row & 7)) << 2);
    } else if (s < 1408) {                  // B region, rows 0..63
      int s2 = s - 896;
      int row = s2 >> 3, t = s2 & 7;
      int rr = row < NCOLS ? row : NCOLS - 1;
      srcb[it] = gt + (size_t)rr * HW + ((t ^ (row & 7)) << 2);
    } else {                                // dummy pad
      srcb[it] = pred + ((s - 1408) << 2);
    }
  }

  auto STAGE = [&](int q, int k0f) {
    unsigned char* bufb = smem + q * BUFBYTES;
#pragma unroll
    for (int it = 0; it < SLOT_ITERS; ++it) {
      const float* src = srcb[it] + k0f;
      unsigned char* dst = bufb + (it * 256 + wid * 64) * 16;
      __builtin_amdgcn_global_load_lds((GU32*)src, (LU32*)dst, 16, 0, 0);
    }
  };

  f32x4 acc[4][2] = {};

  auto COMPUTE = [&](int q) {
    const unsigned char* bufb = smem + q * BUFBYTES;
    bf16x8 bh[2], bl[2];
#pragma unroll
    for (int nf = 0; nf < 2; ++nf) {
      int R = wj * 32 + nf * 16 + r;
      const unsigned char* rowb = bufb + ABYTES + R * 128;
      float4 v0 = *(const float4*)(rowb + (((2 * g    ) ^ (r & 7)) << 4));
      float4 v1 = *(const float4*)(rowb + (((2 * g + 1) ^ (r & 7)) << 4));
      split_frag(v0, v1, bh[nf], bl[nf]);
    }
#pragma unroll
    for (int mf = 0; mf < 4; ++mf) {
      if (wi == 0 || mf < 3) {              // rows 112..127 don't exist
        int R = wi * 64 + mf * 16 + r;
        const unsigned char* rowb = bufb + R * 128;
        float4 v0 = *(const float4*)(rowb + (((2 * g    ) ^ (r & 7)) << 4));
        float4 v1 = *(const float4*)(rowb + (((2 * g + 1) ^ (r & 7)) << 4));
        bf16x8 ah, al;
        split_frag(v0, v1, ah, al);
#pragma unroll
        for (int nf = 0; nf < 2; ++nf) {
          acc[mf][nf] = __builtin_amdgcn_mfma_f32_16x16x32_bf16(ah, bh[nf], acc[mf][nf], 0, 0, 0);
          acc[mf][nf] = __builtin_amdgcn_mfma_f32_16x16x32_bf16(al, bh[nf], acc[mf][nf], 0, 0, 0);
          acc[mf][nf] = __builtin_amdgcn_mfma_f32_16x16x32_bf16(ah, bl[nf], acc[mf][nf], 0, 0, 0);
          acc[mf][nf] = __builtin_amdgcn_mfma_f32_16x16x32_bf16(al, bl[nf], acc[mf][nf], 0, 0, 0);
        }
      }
    }
  };

  STAGE(0, kbase);
  for (int s = 0; s < nst; ++s) {
    // barrier A: all waves finished reading buf[(s+1)&1] (used by stage s-1)
    asm volatile("s_barrier" ::: "memory");
    if (s + 1 < nst) {
      STAGE((s + 1) & 1, kbase + (s + 1) * 32);
      asm volatile("s_waitcnt vmcnt(6)" ::: "memory");   // stage-s loads done
    } else {
      asm volatile("s_waitcnt vmcnt(0)" ::: "memory");
    }
    // barrier B: every wave's stage-s LDS writes have landed
    asm volatile("s_barrier" ::: "memory");
    COMPUTE(s & 1);
  }

  // epilogue: C/D layout col = lane&15, row = 4*(lane>>4)+q
#pragma unroll
  for (int mf = 0; mf < 4; ++mf) {
#pragma unroll
    for (int nf = 0; nf < 2; ++nf) {
#pragma unroll
      for (int qq = 0; qq < 4; ++qq) {
        int row = wi * 64 + mf * 16 + g * 4 + qq;
        int col = wj * 32 + nf * 16 + r;
        if (row < MROWS && col < NCOLS)
          partial[(size_t)b * OUTSZ + row * NCOLS + col] = acc[mf][nf][qq];
      }
    }
  }
}

// ---------------------------------------------------------------------------
// Phase 2a: sum partials over blocks. One wave per 4 consecutive p (float4
// loads, fully coalesced per row), shuffle tree in double.
// ---------------------------------------------------------------------------
__global__ void dm_reduce(const float* __restrict__ partial,
                          double* __restrict__ la0, int nblk) {
  const int tid = threadIdx.x, wid = tid >> 6, lane = tid & 63;
  const int pbase = blockIdx.x * 16 + wid * 4;
  if (pbase >= OUTSZ) return;               // uniform per wave
  double d0 = 0, d1 = 0, d2 = 0, d3 = 0;
  for (int b = lane; b < nblk; b += 64) {
    float4 v = *(const float4*)(partial + (size_t)b * OUTSZ + pbase);
    d0 += (double)v.x; d1 += (double)v.y; d2 += (double)v.z; d3 += (double)v.w;
  }
#pragma unroll
  for (int off = 32; off; off >>= 1) {
    d0 += __shfl_xor(d0, off);
    d1 += __shfl_xor(d1, off);
    d2 += __shfl_xor(d2, off);
    d3 += __shfl_xor(d3, off);
  }
  if (lane == 0) {
    la0[pbase + 0] = (d0 - 1.0) * 10.0;     // -(1-dot)/0.1
    la0[pbase + 1] = (d1 - 1.0) * 10.0;
    la0[pbase + 2] = (d2 - 1.0) * 10.0;
    la0[pbase + 3] = (d3 - 1.0) * 10.0;
  }
}

// ---------------------------------------------------------------------------
// Phase 2b: Sinkhorn as dual potentials. la = la0 - r_i - c_j, r/c in double;
// all exps on (double-subtracted, float-cast) args via fast __expf.
//   iter: r_i = lse_j(la0 - c_j);  c_j = lse_i(la0 - r_i)   (c init 0)
// ---------------------------------------------------------------------------
__global__ __launch_bounds__(256) void dm_sinkhorn(const double* __restrict__ la_in,
                                                   float* __restrict__ out) {
  __shared__ double la[OUTSZ];
  __shared__ double rp[MROWS];
  __shared__ double cp[NCOLS];
  const int t = threadIdx.x;
  for (int p = t; p < OUTSZ; p += 256) la[p] = la_in[p];
  if (t < NCOLS) cp[t] = 0.0;
  __syncthreads();
  for (int it = 0; it < 5; ++it) {
    // rows: 2 lanes per row
    if (t < 2 * MROWS) {
      int row = t >> 1, sl = t & 1;
      double m = -1e300;
      for (int j = sl; j < NCOLS; j += 2) m = fmax(m, la[row * NCOLS + j] - cp[j]);
      float s = 0.f;
      for (int j = sl; j < NCOLS; j += 2)
        s += __expf((float)(la[row * NCOLS + j] - cp[j] - m));
      double mo = __shfl_xor(m, 1); float so = __shfl_xor(s, 1);
      double mn = fmax(m, mo);
      s = s * __expf((float)(m - mn)) + so * __expf((float)(mo - mn));
      if (sl == 0) rp[row] = mn + (double)__logf(s);
    }
    __syncthreads();
    // cols: 4 lanes per col
    if (t < 4 * NCOLS) {
      int col = t >> 2, sl = t & 3;
      double m = -1e300;
      for (int i = sl; i < MROWS; i += 4) m = fmax(m, la[i * NCOLS + col] - rp[i]);
      float s = 0.f;
      for (int i = sl; i < MROWS; i += 4)
        s += __expf((float)(la[i * NCOLS + col] - rp[i] - m));
#pragma unroll
      for (int off = 1; off < 4; off <<= 1) {
        double mo = __shfl_xor(m, off); float so = __shfl_xor(s, off);
        double mn = fmax(m, mo);
        s = s * __expf((float)(m - mn)) + so * __expf((float)(mo - mn));
        m = mn;
      }
      if (sl == 0) cp[col] = m + (double)__logf(s);
    }
    __syncthreads();
  }
  for (int p = t; p < OUTSZ; p += 256)
    out[p] = __expf((float)(la[p] - rp[p / NCOLS] - cp[p % NCOLS]));
}

extern "C" void kernel_launch(void* const* d_in, const int* in_sizes, int n_in,
                              void* d_out, int out_size, void* d_ws, size_t ws_size,
                              hipStream_t stream) {
  const float* pred = (const float*)d_in[0];   // [1,100,512,512] fp32
  const float* gt   = (const float*)d_in[1];   // [50,512,512]    fp32
  float* out = (float*)d_out;                  // [1,100,50]      fp32

  int nblk = 512;
  while (nblk > 1 &&
         ((size_t)nblk * OUTSZ * sizeof(float) + OUTSZ * sizeof(double)) > ws_size)
    nblk >>= 1;
  int chunk = HW / nblk;                       // pow2, multiple of 32

  float*  partial = (float*)d_ws;
  double* la0 = (double*)((char*)d_ws + (size_t)nblk * OUTSZ * sizeof(float));

  dm_phase1<<<nblk, 256, 0, stream>>>(pred, gt, partial, chunk);
  dm_reduce<<<(OUTSZ + 15) / 16, 256, 0, stream>>>(partial, la0, nblk);
  dm_sinkhorn<<<1, 256, 0, stream>>>(la0, out);
}

// Round 4
// 80.132 us; speedup vs baseline: 3.0766x; 1.0698x over previous
//
#include <hip/hip_runtime.h>
#include <math.h>

#define HW       262144
#define TOTSTEPS (HW / 32)
#define MROWS    100
#define NCOLS    50
#define OUTSZ    (MROWS * NCOLS)

typedef __attribute__((ext_vector_type(8))) _Float16 f16x8;
typedef __attribute__((ext_vector_type(2))) __fp16   fp16x2;   // cvt_pkrtz return type
typedef __attribute__((ext_vector_type(4))) float    f32x4;

#define ABYTES   14336              // A: 112 rows * 128 B
#define BUFBYTES 22528              // + B: 64 rows * 128 B
// slots of 16 B: A 0..895, B 896..1407 (1408 total)

typedef __attribute__((address_space(1))) const unsigned int GU32;
typedef __attribute__((address_space(3))) unsigned int LU32;

// f16 two-term split: hi = RTZ_f16(x), lo = RTZ_f16(x - hi).
// |x - hi - lo| <= ~2^-22|x|; dropped lo*lo term ~2^-22 -> 3 MFMA passes.
__device__ __forceinline__ void split_f16(const float4& v0, const float4& v1,
                                          f16x8& hi, f16x8& lo) {
  float xs[8] = {v0.x, v0.y, v0.z, v0.w, v1.x, v1.y, v1.z, v1.w};
  union { fp16x2 p[4]; f16x8 v; } H, L;
#pragma unroll
  for (int j = 0; j < 4; ++j) {
    H.p[j] = __builtin_amdgcn_cvt_pkrtz(xs[2 * j], xs[2 * j + 1]);
    float l0 = xs[2 * j]     - (float)H.p[j][0];
    float l1 = xs[2 * j + 1] - (float)H.p[j][1];
    L.p[j] = __builtin_amdgcn_cvt_pkrtz(l0, l1);
  }
  hi = H.v; lo = L.v;
}

// ---------------------------------------------------------------------------
// Phase 1: LDS-staged split-K GEMM, 768 blocks (3/CU), 4 waves (2x2),
// BK=32 fp32, double-buffered 45056 B LDS. Minimal 2-phase schedule:
//   STAGE(t+1); COMPUTE(t); vmcnt(0); s_barrier   (one barrier per stage)
// global_load_lds(16B): linear LDS dest, inverse-XOR-swizzled global source;
// ds_read_b128 with slot ^= (row&7) -> uniform bank spread.
// ---------------------------------------------------------------------------
__global__ __launch_bounds__(256, 3) void dm_phase1(
    const float* __restrict__ pred, const float* __restrict__ gt,
    float* __restrict__ partial, int nblk) {
  __shared__ unsigned char smem[2 * BUFBYTES];

  const int b    = blockIdx.x;
  const int tid  = threadIdx.x;
  const int lane = tid & 63;
  const int wid  = tid >> 6;
  const int wi = wid >> 1, wj = wid & 1;
  const int g = lane >> 4, r = lane & 15;

  const int k0s = (int)(((long)b * TOTSTEPS) / nblk);
  const int k1s = (int)(((long)(b + 1) * TOTSTEPS) / nblk);
  const int nst = k1s - k0s;

  // per-lane staging source pointers (slot -> global addr, xor-preswizzled)
  const float* srcb[6];
#pragma unroll
  for (int it = 0; it < 6; ++it) {
    int s = (it < 5) ? it * 256 + tid : 1280 + tid;
    const float* p;
    if (s < 896) {                       // A rows 0..111 (dups clamp to 99)
      int row = s >> 3, t = s & 7;
      int rr = row < MROWS ? row : MROWS - 1;
      p = pred + (size_t)rr * HW + ((t ^ (row & 7)) << 2);
    } else {                             // B rows 0..63 (dups clamp to 49)
      int s2 = s - 896;
      int row = s2 >> 3, t = s2 & 7;
      int rr = row < NCOLS ? row : NCOLS - 1;
      p = gt + (size_t)rr * HW + ((t ^ (row & 7)) << 2);
    }
    srcb[it] = p;
  }

  auto STAGE = [&](int q, int kf) {      // kf = k-offset in floats
    unsigned char* bufb = smem + q * BUFBYTES;
#pragma unroll
    for (int it = 0; it < 5; ++it)
      __builtin_amdgcn_global_load_lds((GU32*)(srcb[it] + kf),
          (LU32*)(bufb + (it * 256 + wid * 64) * 16), 16, 0, 0);
    if (wid < 2)                         // slots 1280..1407 (waves 0,1 only)
      __builtin_amdgcn_global_load_lds((GU32*)(srcb[5] + kf),
          (LU32*)(bufb + (1280 + wid * 64) * 16), 16, 0, 0);
  };

  f32x4 acc[4][2] = {};

  auto COMPUTE = [&](int q) {
    const unsigned char* bufb = smem + q * BUFBYTES;
    f16x8 bh[2], bl[2];
#pragma unroll
    for (int nf = 0; nf < 2; ++nf) {
      int R = wj * 32 + nf * 16 + r;
      const unsigned char* rowb = bufb + ABYTES + R * 128;
      float4 v0 = *(const float4*)(rowb + (((2 * g    ) ^ (r & 7)) << 4));
      float4 v1 = *(const float4*)(rowb + (((2 * g + 1) ^ (r & 7)) << 4));
      split_f16(v0, v1, bh[nf], bl[nf]);
    }
#pragma unroll
    for (int mf = 0; mf < 4; ++mf) {
      if (wi == 0 || mf < 3) {           // rows 112..127 don't exist
        int R = wi * 64 + mf * 16 + r;
        const unsigned char* rowb = bufb + R * 128;
        float4 v0 = *(const float4*)(rowb + (((2 * g    ) ^ (r & 7)) << 4));
        float4 v1 = *(const float4*)(rowb + (((2 * g + 1) ^ (r & 7)) << 4));
        f16x8 ah, al;
        split_f16(v0, v1, ah, al);
#pragma unroll
        for (int nf = 0; nf < 2; ++nf) {
          acc[mf][nf] = __builtin_amdgcn_mfma_f32_16x16x32_f16(ah, bh[nf], acc[mf][nf], 0, 0, 0);
          acc[mf][nf] = __builtin_amdgcn_mfma_f32_16x16x32_f16(al, bh[nf], acc[mf][nf], 0, 0, 0);
          acc[mf][nf] = __builtin_amdgcn_mfma_f32_16x16x32_f16(ah, bl[nf], acc[mf][nf], 0, 0, 0);
        }
      }
    }
  };

  STAGE(0, k0s << 5);
  asm volatile("s_waitcnt vmcnt(0)" ::: "memory");
  __builtin_amdgcn_s_barrier();

  int q = 0;
  for (int s = 0; s < nst; ++s) {
    if (s + 1 < nst) STAGE(q ^ 1, (k0s + s + 1) << 5);
    COMPUTE(q);
    if (s + 1 < nst) asm volatile("s_waitcnt vmcnt(0)" ::: "memory");
    __builtin_amdgcn_s_barrier();
    q ^= 1;
  }

  // epilogue: C/D layout col = lane&15, row = 4*(lane>>4)+reg
#pragma unroll
  for (int mf = 0; mf < 4; ++mf) {
#pragma unroll
    for (int nf = 0; nf < 2; ++nf) {
#pragma unroll
      for (int qq = 0; qq < 4; ++qq) {
        int row = wi * 64 + mf * 16 + g * 4 + qq;
        int col = wj * 32 + nf * 16 + r;
        if (row < MROWS && col < NCOLS)
          partial[(size_t)b * OUTSZ + row * NCOLS + col] = acc[mf][nf][qq];
      }
    }
  }
}

// ---------------------------------------------------------------------------
// Phase 2a: sum partials over blocks. One wave per 4 consecutive p; all NB/64
// float4 loads issued independently (in flight together), reduce in double.
// ---------------------------------------------------------------------------
template <int NB>
__global__ void dm_reduce(const float* __restrict__ partial,
                          double* __restrict__ la0) {
  const int tid = threadIdx.x, wid = tid >> 6, lane = tid & 63;
  const int pbase = blockIdx.x * 16 + wid * 4;
  if (pbase >= OUTSZ) return;             // uniform per wave
  constexpr int IT = NB / 64;
  float4 v[IT];
#pragma unroll
  for (int i = 0; i < IT; ++i)
    v[i] = *(const float4*)(partial + (size_t)(lane + 64 * i) * OUTSZ + pbase);
  double d0 = 0, d1 = 0, d2 = 0, d3 = 0;
#pragma unroll
  for (int i = 0; i < IT; ++i) {
    d0 += (double)v[i].x; d1 += (double)v[i].y;
    d2 += (double)v[i].z; d3 += (double)v[i].w;
  }
#pragma unroll
  for (int off = 32; off; off >>= 1) {
    d0 += __shfl_xor(d0, off);
    d1 += __shfl_xor(d1, off);
    d2 += __shfl_xor(d2, off);
    d3 += __shfl_xor(d3, off);
  }
  if (lane == 0) {
    la0[pbase + 0] = (d0 - 1.0) * 10.0;   // -(1-dot)/0.1
    la0[pbase + 1] = (d1 - 1.0) * 10.0;
    la0[pbase + 2] = (d2 - 1.0) * 10.0;
    la0[pbase + 3] = (d3 - 1.0) * 10.0;
  }
}

// ---------------------------------------------------------------------------
// Phase 2b: Sinkhorn via dual potentials (double), fast __expf on f32 deltas.
// ---------------------------------------------------------------------------
__global__ __launch_bounds__(256) void dm_sinkhorn(const double* __restrict__ la_in,
                                                   float* __restrict__ out) {
  __shared__ double la[OUTSZ];
  __shared__ double rp[MROWS];
  __shared__ double cp[NCOLS];
  const int t = threadIdx.x;
  for (int p = t; p < OUTSZ; p += 256) la[p] = la_in[p];
  if (t < NCOLS) cp[t] = 0.0;
  __syncthreads();
  for (int it = 0; it < 5; ++it) {
    if (t < 2 * MROWS) {                  // rows: 2 lanes per row
      int row = t >> 1, sl = t & 1;
      double m = -1e300;
      for (int j = sl; j < NCOLS; j += 2) m = fmax(m, la[row * NCOLS + j] - cp[j]);
      float s = 0.f;
      for (int j = sl; j < NCOLS; j += 2)
        s += __expf((float)(la[row * NCOLS + j] - cp[j] - m));
      double mo = __shfl_xor(m, 1); float so = __shfl_xor(s, 1);
      double mn = fmax(m, mo);
      s = s * __expf((float)(m - mn)) + so * __expf((float)(mo - mn));
      if (sl == 0) rp[row] = mn + (double)__logf(s);
    }
    __syncthreads();
    if (t < 4 * NCOLS) {                  // cols: 4 lanes per col
      int col = t >> 2, sl = t & 3;
      double m = -1e300;
      for (int i = sl; i < MROWS; i += 4) m = fmax(m, la[i * NCOLS + col] - rp[i]);
      float s = 0.f;
      for (int i = sl; i < MROWS; i += 4)
        s += __expf((float)(la[i * NCOLS + col] - rp[i] - m));
#pragma unroll
      for (int off = 1; off < 4; off <<= 1) {
        double mo = __shfl_xor(m, off); float so = __shfl_xor(s, off);
        double mn = fmax(m, mo);
        s = s * __expf((float)(m - mn)) + so * __expf((float)(mo - mn));
        m = mn;
      }
      if (sl == 0) cp[col] = m + (double)__logf(s);
    }
    __syncthreads();
  }
  for (int p = t; p < OUTSZ; p += 256)
    out[p] = __expf((float)(la[p] - rp[p / NCOLS] - cp[p % NCOLS]));
}

extern "C" void kernel_launch(void* const* d_in, const int* in_sizes, int n_in,
                              void* d_out, int out_size, void* d_ws, size_t ws_size,
                              hipStream_t stream) {
  const float* pred = (const float*)d_in[0];   // [1,100,512,512] fp32
  const float* gt   = (const float*)d_in[1];   // [50,512,512]    fp32
  float* out = (float*)d_out;                  // [1,100,50]      fp32

  auto fits = [&](int nb) {
    return ((size_t)nb * OUTSZ * sizeof(float) + OUTSZ * sizeof(double)) <= ws_size;
  };
  int nblk = fits(768) ? 768 : (fits(512) ? 512 : 256);

  float*  partial = (float*)d_ws;
  double* la0 = (double*)((char*)d_ws + (size_t)nblk * OUTSZ * sizeof(float));

  dm_phase1<<<nblk, 256, 0, stream>>>(pred, gt, partial, nblk);
  if (nblk == 768)      dm_reduce<768><<<(OUTSZ + 15) / 16, 256, 0, stream>>>(partial, la0);
  else if (nblk == 512) dm_reduce<512><<<(OUTSZ + 15) / 16, 256, 0, stream>>>(partial, la0);
  else                  dm_reduce<256><<<(OUTSZ + 15) / 16, 256, 0, stream>>>(partial, la0);
  dm_sinkhorn<<<1, 256, 0, stream>>>(la0, out);
}

// Round 5
// 76.176 us; speedup vs baseline: 3.2364x; 1.0519x over previous
//
#include <hip/hip_runtime.h>
#include <math.h>

#define HW       262144
#define TOTSTEPS (HW / 32)
#define MROWS    100
#define NCOLS    50
#define OUTSZ    (MROWS * NCOLS)

typedef __attribute__((ext_vector_type(8))) _Float16 f16x8;
typedef __attribute__((ext_vector_type(2))) __fp16   fp16x2;   // cvt_pkrtz return type
typedef __attribute__((ext_vector_type(4))) float    f32x4;

// LDS buffer: A rows 0..99 (slots 0..799), B rows 0..49 (slots 800..1199),
// pad slots 1200..1279. 1280 slots * 16 B = 20480 B per buffer, ring of 3.
#define ABYTES   12800
#define BUFBYTES 20480

typedef __attribute__((address_space(1))) const unsigned int GU32;
typedef __attribute__((address_space(3))) unsigned int LU32;

// f16 two-term split: hi = RTZ_f16(x), lo = RTZ_f16(x - hi).
__device__ __forceinline__ void split_f16(const float4& v0, const float4& v1,
                                          f16x8& hi, f16x8& lo) {
  float xs[8] = {v0.x, v0.y, v0.z, v0.w, v1.x, v1.y, v1.z, v1.w};
  union { fp16x2 p[4]; f16x8 v; } H, L;
#pragma unroll
  for (int j = 0; j < 4; ++j) {
    H.p[j] = __builtin_amdgcn_cvt_pkrtz(xs[2 * j], xs[2 * j + 1]);
    float l0 = xs[2 * j]     - (float)H.p[j][0];
    float l1 = xs[2 * j + 1] - (float)H.p[j][1];
    L.p[j] = __builtin_amdgcn_cvt_pkrtz(l0, l1);
  }
  hi = H.v; lo = L.v;
}

// ---------------------------------------------------------------------------
// Phase 1: LDS-staged split-K GEMM, 512 blocks (2/CU), 4 waves (2x2 grid),
// BK=32 fp32, TRIPLE-buffered ring (61440 B LDS). Counted-vmcnt schedule
// (T3/T4): per stage  vmcnt(5) -> s_barrier -> COMPUTE(s) -> STAGE(s+2).
// Loads for stage s+2 stay in flight across 2 barriers; never drain to 0
// in the main loop. global_load_lds(16B): linear LDS dest, inverse-XOR-
// swizzled global source; reads use slot j ^ (row&7).
// ---------------------------------------------------------------------------
__global__ __launch_bounds__(256, 2) void dm_phase1(
    const float* __restrict__ pred, const float* __restrict__ gt,
    float* __restrict__ partial, int nblk) {
  __shared__ unsigned char smem[3 * BUFBYTES];

  const int b    = blockIdx.x;
  const int tid  = threadIdx.x;
  const int lane = tid & 63;
  const int wid  = tid >> 6;
  const int wi = wid >> 1, wj = wid & 1;
  const int g = lane >> 4, r = lane & 15;

  const int k0s = (int)(((long)b * TOTSTEPS) / nblk);
  const int k1s = (int)(((long)(b + 1) * TOTSTEPS) / nblk);
  const int nst = k1s - k0s;

  // per-lane staging source pointers (slot -> xor-preswizzled global addr)
  const float* srcb[5];
#pragma unroll
  for (int it = 0; it < 5; ++it) {
    int s = it * 256 + tid;              // 0..1279
    const float* p;
    if (s < 800) {                       // A rows 0..99
      int row = s >> 3, t = s & 7;
      p = pred + (size_t)row * HW + ((t ^ (row & 7)) << 2);
    } else if (s < 1200) {               // B rows 0..49
      int s2 = s - 800;
      int row = s2 >> 3, t = s2 & 7;
      p = gt + (size_t)row * HW + ((t ^ (row & 7)) << 2);
    } else {                             // pad slots
      p = pred + ((s - 1200) << 2);
    }
    srcb[it] = p;
  }

  auto STAGE = [&](unsigned char* bufb, int kf) {   // kf = k-offset in floats
#pragma unroll
    for (int it = 0; it < 5; ++it)
      __builtin_amdgcn_global_load_lds((GU32*)(srcb[it] + kf),
          (LU32*)(bufb + (it * 256 + wid * 64) * 16), 16, 0, 0);
  };

  f32x4 acc[4][2] = {};

  auto COMPUTE = [&](const unsigned char* bufb) {
    f16x8 bh[2], bl[2];
#pragma unroll
    for (int nf = 0; nf < 2; ++nf) {
      int R = wj * 32 + nf * 16 + r;
      if (R > NCOLS - 1) R = NCOLS - 1;  // clamped cols -> outputs discarded
      const unsigned char* rowb = bufb + ABYTES + R * 128;
      float4 v0 = *(const float4*)(rowb + (((2 * g    ) ^ (R & 7)) << 4));
      float4 v1 = *(const float4*)(rowb + (((2 * g + 1) ^ (R & 7)) << 4));
      split_f16(v0, v1, bh[nf], bl[nf]);
    }
#pragma unroll
    for (int mf = 0; mf < 4; ++mf) {
      if (wi == 0 || mf < 3) {           // rows 112..127 don't exist
        int R = wi * 64 + mf * 16 + r;
        if (R > MROWS - 1) R = MROWS - 1; // clamped rows -> outputs discarded
        const unsigned char* rowb = bufb + R * 128;
        float4 v0 = *(const float4*)(rowb + (((2 * g    ) ^ (R & 7)) << 4));
        float4 v1 = *(const float4*)(rowb + (((2 * g + 1) ^ (R & 7)) << 4));
        f16x8 ah, al;
        split_f16(v0, v1, ah, al);
#pragma unroll
        for (int nf = 0; nf < 2; ++nf) {
          acc[mf][nf] = __builtin_amdgcn_mfma_f32_16x16x32_f16(ah, bh[nf], acc[mf][nf], 0, 0, 0);
          acc[mf][nf] = __builtin_amdgcn_mfma_f32_16x16x32_f16(al, bh[nf], acc[mf][nf], 0, 0, 0);
          acc[mf][nf] = __builtin_amdgcn_mfma_f32_16x16x32_f16(ah, bl[nf], acc[mf][nf], 0, 0, 0);
        }
      }
    }
  };

  // prologue: 2 stages in flight
  STAGE(smem, k0s << 5);
  if (nst > 1) STAGE(smem + BUFBYTES, (k0s + 1) << 5);

  int qc = 0;                            // ring index of buffer being computed
  for (int s = 0; s < nst; ++s) {
    if (s + 1 < nst) asm volatile("s_waitcnt vmcnt(5)" ::: "memory");
    else             asm volatile("s_waitcnt vmcnt(0)" ::: "memory");
    __builtin_amdgcn_s_barrier();        // all waves' stage-s loads landed
    COMPUTE(smem + qc * BUFBYTES);
    if (s + 2 < nst) {
      int qs = qc + 2; if (qs >= 3) qs -= 3;
      STAGE(smem + qs * BUFBYTES, (k0s + s + 2) << 5);
    }
    qc = (qc == 2) ? 0 : qc + 1;
  }

  // epilogue: C/D layout col = lane&15, row = 4*(lane>>4)+reg
#pragma unroll
  for (int mf = 0; mf < 4; ++mf) {
#pragma unroll
    for (int nf = 0; nf < 2; ++nf) {
#pragma unroll
      for (int qq = 0; qq < 4; ++qq) {
        int row = wi * 64 + mf * 16 + g * 4 + qq;
        int col = wj * 32 + nf * 16 + r;
        if (row < MROWS && col < NCOLS)
          partial[(size_t)b * OUTSZ + row * NCOLS + col] = acc[mf][nf][qq];
      }
    }
  }
}

// ---------------------------------------------------------------------------
// Phase 2a: sum partials over blocks. One wave per 4 consecutive p; all NB/64
// float4 loads issued independently (in flight together), reduce in double.
// ---------------------------------------------------------------------------
template <int NB>
__global__ void dm_reduce(const float* __restrict__ partial,
                          double* __restrict__ la0) {
  const int tid = threadIdx.x, wid = tid >> 6, lane = tid & 63;
  const int pbase = blockIdx.x * 16 + wid * 4;
  if (pbase >= OUTSZ) return;             // uniform per wave
  constexpr int IT = NB / 64;
  float4 v[IT];
#pragma unroll
  for (int i = 0; i < IT; ++i)
    v[i] = *(const float4*)(partial + (size_t)(lane + 64 * i) * OUTSZ + pbase);
  double d0 = 0, d1 = 0, d2 = 0, d3 = 0;
#pragma unroll
  for (int i = 0; i < IT; ++i) {
    d0 += (double)v[i].x; d1 += (double)v[i].y;
    d2 += (double)v[i].z; d3 += (double)v[i].w;
  }
#pragma unroll
  for (int off = 32; off; off >>= 1) {
    d0 += __shfl_xor(d0, off);
    d1 += __shfl_xor(d1, off);
    d2 += __shfl_xor(d2, off);
    d3 += __shfl_xor(d3, off);
  }
  if (lane == 0) {
    la0[pbase + 0] = (d0 - 1.0) * 10.0;   // -(1-dot)/0.1
    la0[pbase + 1] = (d1 - 1.0) * 10.0;
    la0[pbase + 2] = (d2 - 1.0) * 10.0;
    la0[pbase + 3] = (d3 - 1.0) * 10.0;
  }
}

// ---------------------------------------------------------------------------
// Phase 2b: Sinkhorn via dual potentials (double), fast __expf on f32 deltas.
// ---------------------------------------------------------------------------
__global__ __launch_bounds__(256) void dm_sinkhorn(const double* __restrict__ la_in,
                                                   float* __restrict__ out) {
  __shared__ double la[OUTSZ];
  __shared__ double rp[MROWS];
  __shared__ double cp[NCOLS];
  const int t = threadIdx.x;
  for (int p = t; p < OUTSZ; p += 256) la[p] = la_in[p];
  if (t < NCOLS) cp[t] = 0.0;
  __syncthreads();
  for (int it = 0; it < 5; ++it) {
    if (t < 2 * MROWS) {                  // rows: 2 lanes per row
      int row = t >> 1, sl = t & 1;
      double m = -1e300;
      for (int j = sl; j < NCOLS; j += 2) m = fmax(m, la[row * NCOLS + j] - cp[j]);
      float s = 0.f;
      for (int j = sl; j < NCOLS; j += 2)
        s += __expf((float)(la[row * NCOLS + j] - cp[j] - m));
      double mo = __shfl_xor(m, 1); float so = __shfl_xor(s, 1);
      double mn = fmax(m, mo);
      s = s * __expf((float)(m - mn)) + so * __expf((float)(mo - mn));
      if (sl == 0) rp[row] = mn + (double)__logf(s);
    }
    __syncthreads();
    if (t < 4 * NCOLS) {                  // cols: 4 lanes per col
      int col = t >> 2, sl = t & 3;
      double m = -1e300;
      for (int i = sl; i < MROWS; i += 4) m = fmax(m, la[i * NCOLS + col] - rp[i]);
      float s = 0.f;
      for (int i = sl; i < MROWS; i += 4)
        s += __expf((float)(la[i * NCOLS + col] - rp[i] - m));
#pragma unroll
      for (int off = 1; off < 4; off <<= 1) {
        double mo = __shfl_xor(m, off); float so = __shfl_xor(s, off);
        double mn = fmax(m, mo);
        s = s * __expf((float)(m - mn)) + so * __expf((float)(mo - mn));
        m = mn;
      }
      if (sl == 0) cp[col] = m + (double)__logf(s);
    }
    __syncthreads();
  }
  for (int p = t; p < OUTSZ; p += 256)
    out[p] = __expf((float)(la[p] - rp[p / NCOLS] - cp[p % NCOLS]));
}

extern "C" void kernel_launch(void* const* d_in, const int* in_sizes, int n_in,
                              void* d_out, int out_size, void* d_ws, size_t ws_size,
                              hipStream_t stream) {
  const float* pred = (const float*)d_in[0];   // [1,100,512,512] fp32
  const float* gt   = (const float*)d_in[1];   // [50,512,512]    fp32
  float* out = (float*)d_out;                  // [1,100,50]      fp32

  auto fits = [&](int nb) {
    return ((size_t)nb * OUTSZ * sizeof(float) + OUTSZ * sizeof(double)) <= ws_size;
  };
  int nblk = fits(512) ? 512 : 256;

  float*  partial = (float*)d_ws;
  double* la0 = (double*)((char*)d_ws + (size_t)nblk * OUTSZ * sizeof(float));

  dm_phase1<<<nblk, 256, 0, stream>>>(pred, gt, partial, nblk);
  if (nblk == 512) dm_reduce<512><<<(OUTSZ + 15) / 16, 256, 0, stream>>>(partial, la0);
  else             dm_reduce<256><<<(OUTSZ + 15) / 16, 256, 0, stream>>>(partial, la0);
  dm_sinkhorn<<<1, 256, 0, stream>>>(la0, out);
}

// Round 6
// 75.676 us; speedup vs baseline: 3.2578x; 1.0066x over previous
//
#include <hip/hip_runtime.h>
#include <math.h>

#define HW       262144
#define TOTSTEPS (HW / 32)
#define MROWS    100
#define NCOLS    50
#define OUTSZ    (MROWS * NCOLS)

typedef __attribute__((ext_vector_type(8))) _Float16 f16x8;
typedef __attribute__((ext_vector_type(2))) __fp16   fp16x2;   // cvt_pkrtz return type
typedef __attribute__((ext_vector_type(4))) float    f32x4;

// LDS buffer: padded rows of 144 B (128 data + 16 dup-pad).
//   A rows 0..99  -> bytes [0, 14400)        (slots 0..899, 9 per row)
//   B rows 0..49  -> bytes [14400, 21600)    (slots 900..1349)
//   dummy         -> slots 1350..1535
// 1536 slots * 16 B = 24576 B per buffer, ring of 3 (73728 B total).
// Row stride 144 B -> ds_read_b128 banks (36R+8g)%32: 2-way max = free.
// Staging sources are PLAIN ascending row bytes (no swizzle) -> each wave
// instruction = ascending 16B-lane runs of 128-144 B per row (coalescable).
#define ABYTES   14400
#define BUFBYTES 24576

typedef __attribute__((address_space(1))) const unsigned int GU32;
typedef __attribute__((address_space(3))) unsigned int LU32;

// f16 two-term split: hi = RTZ_f16(x), lo = RTZ_f16(x - hi).
__device__ __forceinline__ void split_f16(const float4& v0, const float4& v1,
                                          f16x8& hi, f16x8& lo) {
  float xs[8] = {v0.x, v0.y, v0.z, v0.w, v1.x, v1.y, v1.z, v1.w};
  union { fp16x2 p[4]; f16x8 v; } H, L;
#pragma unroll
  for (int j = 0; j < 4; ++j) {
    H.p[j] = __builtin_amdgcn_cvt_pkrtz(xs[2 * j], xs[2 * j + 1]);
    float l0 = xs[2 * j]     - (float)H.p[j][0];
    float l1 = xs[2 * j + 1] - (float)H.p[j][1];
    L.p[j] = __builtin_amdgcn_cvt_pkrtz(l0, l1);
  }
  hi = H.v; lo = L.v;
}

// ---------------------------------------------------------------------------
// Phase 1: LDS-staged split-K GEMM, 512 blocks (2/CU), 4 waves (2x2 grid),
// BK=32 fp32, triple-buffered ring, counted vmcnt(6) (T3/T4):
//   per stage: vmcnt(6) -> s_barrier -> COMPUTE(s) -> STAGE(s+2)
// ---------------------------------------------------------------------------
__global__ __launch_bounds__(256, 2) void dm_phase1(
    const float* __restrict__ pred, const float* __restrict__ gt,
    float* __restrict__ partial, int nblk) {
  __shared__ unsigned char smem[3 * BUFBYTES];

  const int b    = blockIdx.x;
  const int tid  = threadIdx.x;
  const int lane = tid & 63;
  const int wid  = tid >> 6;
  const int wi = wid >> 1, wj = wid & 1;
  const int g = lane >> 4, r = lane & 15;

  const int k0s = (int)(((long)b * TOTSTEPS) / nblk);
  const int k1s = (int)(((long)(b + 1) * TOTSTEPS) / nblk);
  const int nst = k1s - k0s;

  // per-lane staging source pointers: slot -> plain (unswizzled) global addr
  const float* srcb[6];
#pragma unroll
  for (int it = 0; it < 6; ++it) {
    int s = it * 256 + tid;              // 0..1535
    const float* p;
    if (s < 900) {                       // A rows 0..99
      int row = s / 9;
      int off = (s - row * 9) * 16;      // byte-in-row 0..128
      if (off > 112) off = 112;          // pad slot: dup bytes 112..127
      p = pred + (size_t)row * HW + (off >> 2);
    } else if (s < 1350) {               // B rows 0..49
      int s2 = s - 900;
      int row = s2 / 9;
      int off = (s2 - row * 9) * 16;
      if (off > 112) off = 112;
      p = gt + (size_t)row * HW + (off >> 2);
    } else {                             // dummy slots (one hot line)
      p = pred + ((s - 1350) & 7) * 4;
    }
    srcb[it] = p;
  }

  auto STAGE = [&](unsigned char* bufb, int kf) {   // kf = k-offset in floats
#pragma unroll
    for (int it = 0; it < 6; ++it)
      __builtin_amdgcn_global_load_lds((GU32*)(srcb[it] + kf),
          (LU32*)(bufb + (it * 256 + wid * 64) * 16), 16, 0, 0);
  };

  f32x4 acc[4][2] = {};

  auto COMPUTE = [&](const unsigned char* bufb) {
    f16x8 bh[2], bl[2];
#pragma unroll
    for (int nf = 0; nf < 2; ++nf) {
      int R = wj * 32 + nf * 16 + r;
      if (R > NCOLS - 1) R = NCOLS - 1;  // clamped cols -> outputs discarded
      const unsigned char* rowb = bufb + ABYTES + R * 144;
      float4 v0 = *(const float4*)(rowb + 32 * g);
      float4 v1 = *(const float4*)(rowb + 32 * g + 16);
      split_f16(v0, v1, bh[nf], bl[nf]);
    }
#pragma unroll
    for (int mf = 0; mf < 4; ++mf) {
      if (wi == 0 || mf < 3) {           // rows 112..127 don't exist
        int R = wi * 64 + mf * 16 + r;
        if (R > MROWS - 1) R = MROWS - 1; // clamped rows -> outputs discarded
        const unsigned char* rowb = bufb + R * 144;
        float4 v0 = *(const float4*)(rowb + 32 * g);
        float4 v1 = *(const float4*)(rowb + 32 * g + 16);
        f16x8 ah, al;
        split_f16(v0, v1, ah, al);
#pragma unroll
        for (int nf = 0; nf < 2; ++nf) {
          acc[mf][nf] = __builtin_amdgcn_mfma_f32_16x16x32_f16(ah, bh[nf], acc[mf][nf], 0, 0, 0);
          acc[mf][nf] = __builtin_amdgcn_mfma_f32_16x16x32_f16(al, bh[nf], acc[mf][nf], 0, 0, 0);
          acc[mf][nf] = __builtin_amdgcn_mfma_f32_16x16x32_f16(ah, bl[nf], acc[mf][nf], 0, 0, 0);
        }
      }
    }
  };

  // prologue: 2 stages in flight
  STAGE(smem, k0s << 5);
  if (nst > 1) STAGE(smem + BUFBYTES, (k0s + 1) << 5);

  int qc = 0;                            // ring index of buffer being computed
  for (int s = 0; s < nst; ++s) {
    if (s + 1 < nst) asm volatile("s_waitcnt vmcnt(6)" ::: "memory");
    else             asm volatile("s_waitcnt vmcnt(0)" ::: "memory");
    __builtin_amdgcn_s_barrier();        // all waves' stage-s loads landed
    COMPUTE(smem + qc * BUFBYTES);
    if (s + 2 < nst) {
      int qs = qc + 2; if (qs >= 3) qs -= 3;
      STAGE(smem + qs * BUFBYTES, (k0s + s + 2) << 5);
    }
    qc = (qc == 2) ? 0 : qc + 1;
  }

  // epilogue: C/D layout col = lane&15, row = 4*(lane>>4)+reg
#pragma unroll
  for (int mf = 0; mf < 4; ++mf) {
#pragma unroll
    for (int nf = 0; nf < 2; ++nf) {
#pragma unroll
      for (int qq = 0; qq < 4; ++qq) {
        int row = wi * 64 + mf * 16 + g * 4 + qq;
        int col = wj * 32 + nf * 16 + r;
        if (row < MROWS && col < NCOLS)
          partial[(size_t)b * OUTSZ + row * NCOLS + col] = acc[mf][nf][qq];
      }
    }
  }
}

// ---------------------------------------------------------------------------
// Phase 2a: sum partials over blocks. One wave per 4 consecutive p; all NB/64
// float4 loads issued independently (in flight together), reduce in double.
// ---------------------------------------------------------------------------
template <int NB>
__global__ void dm_reduce(const float* __restrict__ partial,
                          double* __restrict__ la0) {
  const int tid = threadIdx.x, wid = tid >> 6, lane = tid & 63;
  const int pbase = blockIdx.x * 16 + wid * 4;
  if (pbase >= OUTSZ) return;             // uniform per wave
  constexpr int IT = NB / 64;
  float4 v[IT];
#pragma unroll
  for (int i = 0; i < IT; ++i)
    v[i] = *(const float4*)(partial + (size_t)(lane + 64 * i) * OUTSZ + pbase);
  double d0 = 0, d1 = 0, d2 = 0, d3 = 0;
#pragma unroll
  for (int i = 0; i < IT; ++i) {
    d0 += (double)v[i].x; d1 += (double)v[i].y;
    d2 += (double)v[i].z; d3 += (double)v[i].w;
  }
#pragma unroll
  for (int off = 32; off; off >>= 1) {
    d0 += __shfl_xor(d0, off);
    d1 += __shfl_xor(d1, off);
    d2 += __shfl_xor(d2, off);
    d3 += __shfl_xor(d3, off);
  }
  if (lane == 0) {
    la0[pbase + 0] = (d0 - 1.0) * 10.0;   // -(1-dot)/0.1
    la0[pbase + 1] = (d1 - 1.0) * 10.0;
    la0[pbase + 2] = (d2 - 1.0) * 10.0;
    la0[pbase + 3] = (d3 - 1.0) * 10.0;
  }
}

// ---------------------------------------------------------------------------
// Phase 2b: Sinkhorn via dual potentials (double), fast __expf on f32 deltas.
// ---------------------------------------------------------------------------
__global__ __launch_bounds__(256) void dm_sinkhorn(const double* __restrict__ la_in,
                                                   float* __restrict__ out) {
  __shared__ double la[OUTSZ];
  __shared__ double rp[MROWS];
  __shared__ double cp[NCOLS];
  const int t = threadIdx.x;
  for (int p = t; p < OUTSZ; p += 256) la[p] = la_in[p];
  if (t < NCOLS) cp[t] = 0.0;
  __syncthreads();
  for (int it = 0; it < 5; ++it) {
    if (t < 2 * MROWS) {                  // rows: 2 lanes per row
      int row = t >> 1, sl = t & 1;
      double m = -1e300;
      for (int j = sl; j < NCOLS; j += 2) m = fmax(m, la[row * NCOLS + j] - cp[j]);
      float s = 0.f;
      for (int j = sl; j < NCOLS; j += 2)
        s += __expf((float)(la[row * NCOLS + j] - cp[j] - m));
      double mo = __shfl_xor(m, 1); float so = __shfl_xor(s, 1);
      double mn = fmax(m, mo);
      s = s * __expf((float)(m - mn)) + so * __expf((float)(mo - mn));
      if (sl == 0) rp[row] = mn + (double)__logf(s);
    }
    __syncthreads();
    if (t < 4 * NCOLS) {                  // cols: 4 lanes per col
      int col = t >> 2, sl = t & 3;
      double m = -1e300;
      for (int i = sl; i < MROWS; i += 4) m = fmax(m, la[i * NCOLS + col] - rp[i]);
      float s = 0.f;
      for (int i = sl; i < MROWS; i += 4)
        s += __expf((float)(la[i * NCOLS + col] - rp[i] - m));
#pragma unroll
      for (int off = 1; off < 4; off <<= 1) {
        double mo = __shfl_xor(m, off); float so = __shfl_xor(s, off);
        double mn = fmax(m, mo);
        s = s * __expf((float)(m - mn)) + so * __expf((float)(mo - mn));
        m = mn;
      }
      if (sl == 0) cp[col] = m + (double)__logf(s);
    }
    __syncthreads();
  }
  for (int p = t; p < OUTSZ; p += 256)
    out[p] = __expf((float)(la[p] - rp[p / NCOLS] - cp[p % NCOLS]));
}

extern "C" void kernel_launch(void* const* d_in, const int* in_sizes, int n_in,
                              void* d_out, int out_size, void* d_ws, size_t ws_size,
                              hipStream_t stream) {
  const float* pred = (const float*)d_in[0];   // [1,100,512,512] fp32
  const float* gt   = (const float*)d_in[1];   // [50,512,512]    fp32
  float* out = (float*)d_out;                  // [1,100,50]      fp32

  auto fits = [&](int nb) {
    return ((size_t)nb * OUTSZ * sizeof(float) + OUTSZ * sizeof(double)) <= ws_size;
  };
  int nblk = fits(512) ? 512 : 256;

  float*  partial = (float*)d_ws;
  double* la0 = (double*)((char*)d_ws + (size_t)nblk * OUTSZ * sizeof(float));

  dm_phase1<<<nblk, 256, 0, stream>>>(pred, gt, partial, nblk);
  if (nblk == 512) dm_reduce<512><<<(OUTSZ + 15) / 16, 256, 0, stream>>>(partial, la0);
  else             dm_reduce<256><<<(OUTSZ + 15) / 16, 256, 0, stream>>>(partial, la0);
  dm_sinkhorn<<<1, 256, 0, stream>>>(la0, out);
}